// Round 3
// baseline (182.153 us; speedup 1.0000x reference)
//
#include <hip/hip_runtime.h>
#include <hip/hip_bf16.h>

// B=4, G=1024, D=512, H=8, dh=64. NUM_BUCKETS=32, MAX_DIST=128, base=2.
typedef __attribute__((ext_vector_type(8))) short bf16x8;
typedef __attribute__((ext_vector_type(4))) float f32x4;

__device__ __forceinline__ unsigned short f2bf(float x) {
  union { __hip_bfloat16 h; unsigned short u; } cv;
  cv.h = __float2bfloat16(x);
  return cv.u;
}

__device__ __forceinline__ void gload16(const void* g, void* l) {
  __builtin_amdgcn_global_load_lds(
      (const __attribute__((address_space(1))) unsigned int*)g,
      (__attribute__((address_space(3))) unsigned int*)l, 16, 0, 0);
}

// swizzled byte offset for 128B-row LDS tiles
__device__ __forceinline__ int swz128(int row, int colb) {
  return row * 128 + (colb ^ ((row & 7) << 4));
}

// ---------------- fp32 -> bf16 conversion (all tensors, one launch) -------------
__global__ __launch_bounds__(256)
void k_cvt_all(const float* __restrict__ q, const float* __restrict__ k,
               const float* __restrict__ v, const float* __restrict__ Wq,
               const float* __restrict__ Wk, const float* __restrict__ Wv,
               const float* __restrict__ Wo,
               unsigned short* __restrict__ XQ, unsigned short* __restrict__ XK,
               unsigned short* __restrict__ XV, unsigned short* __restrict__ WQB,
               unsigned short* __restrict__ WKB, unsigned short* __restrict__ WVB,
               unsigned short* __restrict__ WOB)
{
  long i = ((long)blockIdx.x * 256 + threadIdx.x) * 8;
  const float* s; unsigned short* d; long off;
  if (i < 2097152)      { s = q; d = XQ; off = i; }
  else if (i < 4194304) { s = k; d = XK; off = i - 2097152; }
  else if (i < 6291456) { s = v; d = XV; off = i - 4194304; }
  else {
    long j = i - 6291456;
    int wsel = (int)(j >> 18);
    off = j & 262143;
    s = wsel == 0 ? Wq : wsel == 1 ? Wk : wsel == 2 ? Wv : Wo;
    d = wsel == 0 ? WQB : wsel == 1 ? WKB : wsel == 2 ? WVB : WOB;
  }
  float4 a = *(const float4*)(s + off);
  float4 bb = *(const float4*)(s + off + 4);
  bf16x8 o;
  o[0] = (short)f2bf(a.x);  o[1] = (short)f2bf(a.y);
  o[2] = (short)f2bf(a.z);  o[3] = (short)f2bf(a.w);
  o[4] = (short)f2bf(bb.x); o[5] = (short)f2bf(bb.y);
  o[6] = (short)f2bf(bb.z); o[7] = (short)f2bf(bb.w);
  *(bf16x8*)(d + off) = o;
}

// ---------------- per-batch valid-key compaction (prefix scan) ------------------
__global__ __launch_bounds__(1024)
void k_scan(const int* __restrict__ mask, int* __restrict__ idx, int* __restrict__ cnt) {
  __shared__ int ps[1024];
  int b = blockIdx.x, t = threadIdx.x;
  int m = mask[(b << 10) + t];
  ps[t] = m;
  __syncthreads();
  #pragma unroll
  for (int off = 1; off < 1024; off <<= 1) {
    int v = (t >= off) ? ps[t - off] : 0;
    __syncthreads();
    ps[t] += v;
    __syncthreads();
  }
  if (m) idx[(b << 10) + ps[t] - 1] = t;
  if (t == 1023) cnt[b] = ps[t];
}

// ---------------- compacted buckets: combined idx, permuted for coalesced reads --
__device__ __forceinline__ int rbucket(float dd) {
  float ad = fabsf(dd);
  float n = fminf(fmaxf(ad, 1e-6f), 128.0f);
  int li = (int)floorf(logf(n) * 1.4426950408889634f);
  li = li < 0 ? 0 : (li > 31 ? 31 : li);
  int s = (dd > 0.f) ? 1 : ((dd < 0.f) ? -1 : 0);
  return li * s + 31;
}

__global__ __launch_bounds__(256)
void k_buckets_c(const float* __restrict__ coords, const int* __restrict__ idx,
                 const int* __restrict__ cnt, unsigned short* __restrict__ buk) {
  int b = blockIdx.y;
  int f = blockIdx.x * 256 + threadIdx.x;   // q*1024 + ck
  int qi = f >> 10, ck = f & 1023;
  int cn = cnt[b];
  int cnp = (cn + 63) & ~63;                // padded to 64
  if (ck >= cnp) return;
  // permutation within 64-key chunk: pos = (k&15)*4 + (k>>4)&3 so that a lane's
  // 8B read at l15*4 yields keys {nj*16+l15 : nj=0..3}
  int pos = (ck & ~63) | ((ck & 15) << 2) | ((ck >> 4) & 3);
  unsigned short val = 0;
  if (ck < cn) {
    int ki = idx[(b << 10) + ck];
    const float* cb = coords + (b << 11);
    float dx = cb[qi * 2]     - cb[ki * 2];
    float dy = cb[qi * 2 + 1] - cb[ki * 2 + 1];
    val = (unsigned short)(rbucket(dx) * 63 + rbucket(dy));
  }
  buk[((long)(b << 10) + qi) * 1024 + pos] = val;
}

// ---------------- gather compacted K rows + transposed V ------------------------
__global__ __launch_bounds__(256)
void k_gatherKV(const unsigned short* __restrict__ KP,
                const unsigned short* __restrict__ VTMP,
                const int* __restrict__ idx, const int* __restrict__ cnt,
                unsigned short* __restrict__ KC, unsigned short* __restrict__ VCT)
{
  __shared__ unsigned short tile[64][68];
  __shared__ int lidx[64];
  int bh = blockIdx.y, b = bh >> 3;
  int cn = cnt[b];
  int ck0 = blockIdx.x << 6;
  if (ck0 >= cn) return;
  int t = threadIdx.x;
  if (t < 64) lidx[t] = idx[(b << 10) + min(ck0 + t, cn - 1)];
  __syncthreads();
  int r = t >> 2, qd = t & 3;
  long srcrow = ((long)(bh << 10) + lidx[r]) * 64;
  long dstrow = ((long)(bh << 10) + ck0 + r) * 64;
  uint4 kv0 = *(const uint4*)(KP + srcrow + qd * 16);
  uint4 kv1 = *(const uint4*)(KP + srcrow + qd * 16 + 8);
  *(uint4*)(KC + dstrow + qd * 16) = kv0;
  *(uint4*)(KC + dstrow + qd * 16 + 8) = kv1;
  const uint2* vsrc = (const uint2*)(VTMP + srcrow + qd * 16);
  #pragma unroll
  for (int s = 0; s < 4; ++s)
    *(uint2*)(&tile[r][qd * 16 + s * 4]) = vsrc[s];
  __syncthreads();
  #pragma unroll
  for (int it = 0; it < 16; ++it) {
    int d = it * 4 + (t >> 6);
    int ck = t & 63;
    VCT[((long)(bh << 6) + d) * 1024 + ck0 + ck] = tile[ck][d];
  }
}

// ---------------- GEMM core: C = A(M,512) @ Bw(N,512)^T, 128x64 tile, 4 waves ---
__device__ __forceinline__ void gemm_core64(
    const unsigned short* __restrict__ A, const unsigned short* __restrict__ Bw,
    int m0, int n0, unsigned short* ldsA, unsigned short* ldsB, f32x4 acc[4][2])
{
  const int t = threadIdx.x;
  const int lane = t & 63;
  const int w = t >> 6;
  const int wm = (w >> 1) << 6;
  const int wn = (w & 1) << 5;
  const int l15 = lane & 15;
  const int l4 = lane >> 4;
  const f32x4 fz = {0.f, 0.f, 0.f, 0.f};

  #pragma unroll
  for (int r = 0; r < 4; ++r)
    #pragma unroll
    for (int c = 0; c < 2; ++c) acc[r][c] = fz;

  for (int k0 = 0; k0 < 512; k0 += 32) {
    #pragma unroll
    for (int rr = 0; rr < 2; ++rr) {
      int c = rr * 256 + t;
      int row = c >> 2, cc = c & 3;
      gload16(A + (m0 + row) * 512 + k0 + cc * 8, (char*)ldsA + c * 16);
    }
    {
      int c = t;
      int row = c >> 2, cc = c & 3;
      gload16(Bw + (n0 + row) * 512 + k0 + cc * 8, (char*)ldsB + c * 16);
    }
    __syncthreads();
    bf16x8 af[4], bfr[2];
    #pragma unroll
    for (int r = 0; r < 4; ++r)
      af[r] = *(const bf16x8*)((const char*)ldsA + (wm + r * 16 + l15) * 64 + l4 * 16);
    #pragma unroll
    for (int c = 0; c < 2; ++c)
      bfr[c] = *(const bf16x8*)((const char*)ldsB + (wn + c * 16 + l15) * 64 + l4 * 16);
    #pragma unroll
    for (int r = 0; r < 4; ++r)
      #pragma unroll
      for (int c = 0; c < 2; ++c)
        acc[r][c] = __builtin_amdgcn_mfma_f32_16x16x32_bf16(af[r], bfr[c], acc[r][c], 0, 0, 0);
    __syncthreads();
  }
}

// ---------------- Q/K/V projections -> (B,H,G,64) bf16 --------------------------
__global__ __launch_bounds__(256)
void k_gemm_proj(const unsigned short* __restrict__ XQ, const unsigned short* __restrict__ XK,
                 const unsigned short* __restrict__ XV, const unsigned short* __restrict__ WQ,
                 const unsigned short* __restrict__ WK, const unsigned short* __restrict__ WV,
                 const float* __restrict__ bq, const float* __restrict__ bk,
                 const float* __restrict__ bv,
                 unsigned short* __restrict__ QP, unsigned short* __restrict__ KP,
                 unsigned short* __restrict__ VT)
{
  __shared__ unsigned short ldsA[128 * 32];
  __shared__ unsigned short ldsB[64 * 32];
  int z = blockIdx.z;
  const unsigned short* A = z == 0 ? XQ : z == 1 ? XK : XV;
  const unsigned short* W = z == 0 ? WQ : z == 1 ? WK : WV;
  const float* bias = z == 0 ? bq : z == 1 ? bk : bv;
  unsigned short* dst = z == 0 ? QP : z == 1 ? KP : VT;
  int m0 = blockIdx.x * 128, n0 = blockIdx.y * 64;
  f32x4 acc[4][2];
  gemm_core64(A, W, m0, n0, ldsA, ldsB, acc);

  const int t = threadIdx.x, lane = t & 63, w = t >> 6;
  const int wm = (w >> 1) << 6, wn = (w & 1) << 5;
  const int l15 = lane & 15, l4 = lane >> 4;
  #pragma unroll
  for (int r = 0; r < 4; ++r)
    #pragma unroll
    for (int c = 0; c < 2; ++c)
      #pragma unroll
      for (int i = 0; i < 4; ++i) {
        int m = m0 + wm + r * 16 + (l4 << 2) + i;   // token
        int n = n0 + wn + c * 16 + l15;             // channel
        float y = acc[r][c][i] + bias[n];
        int b = m >> 10, g = m & 1023, hh = n >> 6, dd = n & 63;
        dst[((((b << 3) + hh) << 10) + g) * 64 + dd] = f2bf(y);
      }
}

// ---------------- flash attention: 8 waves, key-split halves, LDS merge ---------
// grid 512 blocks x 512 threads. Waves w and w+4 share 16 q rows, split keys.
__global__ __launch_bounds__(512, 4)
void k_attn(const unsigned short* __restrict__ QP, const unsigned short* __restrict__ KC,
            const unsigned short* __restrict__ VCT, const unsigned short* __restrict__ BUKC,
            const int* __restrict__ cnt, const float* __restrict__ rpe_x,
            const float* __restrict__ rpe_y, unsigned short* __restrict__ AO)
{
  __shared__ float biasT[3969];              // per-head rx[bx]+ry[by] table
  __shared__ unsigned short Ps[8][1024];     // per-wave P-transpose, swizzled
  __shared__ float O2[4][16][68];            // key-half-1 partial O (padded stride)
  __shared__ float M2[4][16];
  __shared__ float L2s[4][16];

  const int t = threadIdx.x;
  const int lane = t & 63;
  const int w = t >> 6;          // 0..7
  const int rg = w & 3;          // row-group (16 q rows)
  const int kh = w >> 2;         // key half
  const int l15 = lane & 15;
  const int l4 = lane >> 4;
  const f32x4 fz = {0.f, 0.f, 0.f, 0.f};

  // XCD swizzle: each XCD handles one (batch, q-half) -> K/V/BUKC L2 locality
  int g = blockIdx.x;
  int xcd = g & 7, slot = g >> 3;
  int b = xcd >> 1;
  int qb = ((xcd & 1) << 3) | (slot & 7);   // 0..15 (64-row blocks)
  int h = slot >> 3;
  int bh = (b << 3) | h;
  int qw = (qb << 6) | (rg << 4);           // wave's q-row base in [0,1024)

  for (int j = t; j < 3969; j += 512) {
    int bx = j / 63, by = j - bx * 63;
    biasT[j] = rpe_x[bx * 8 + h] + rpe_y[by * 8 + h];
  }
  __syncthreads();

  const unsigned short* Qg = QP + ((long)(bh << 10) + qw) * 64;
  bf16x8 qf[2];
  #pragma unroll
  for (int ks = 0; ks < 2; ++ks)
    qf[ks] = *(const bf16x8*)(Qg + (long)l15 * 64 + ks * 32 + l4 * 8);

  const int cn = cnt[b];
  const int nkt = (cn + 63) >> 6;
  const int nk0 = (nkt + 1) >> 1;
  const int ktb = kh ? nk0 : 0;
  const int kte = kh ? nkt : nk0;
  const unsigned short* Kg = KC + ((long)(bh << 10)) * 64;
  const unsigned short* Vg = VCT + ((long)(bh << 6)) * 1024;
  const unsigned short* bukb = BUKC + ((long)(b << 10) + qw) * 1024;

  float mrun[4], lrun[4];
  f32x4 oacc[4];
  #pragma unroll
  for (int i = 0; i < 4; ++i) { mrun[i] = -1e30f; lrun[i] = 0.f; }
  #pragma unroll
  for (int dj = 0; dj < 4; ++dj) oacc[dj] = fz;

  unsigned short* Pw = &Ps[w][0];

  for (int kt = ktb; kt < kte; ++kt) {
    const int k0 = kt << 6;
    // coalesced bucket fragment loads: one 8B load per row -> 4 keys per lane
    unsigned bko[4][4];
    #pragma unroll
    for (int i = 0; i < 4; ++i) {
      uint2 bv = *(const uint2*)(bukb + ((l4 << 2) + i) * 1024 + k0 + (l15 << 2));
      bko[i][0] = bv.x & 0xffff; bko[i][1] = bv.x >> 16;
      bko[i][2] = bv.y & 0xffff; bko[i][3] = bv.y >> 16;
    }
    int vmask[4];
    #pragma unroll
    for (int nj = 0; nj < 4; ++nj) vmask[nj] = (k0 + nj * 16 + l15) < cn;

    // S = Q K^T from global K fragments (L2-resident)
    f32x4 sacc[4];
    #pragma unroll
    for (int nj = 0; nj < 4; ++nj) sacc[nj] = fz;
    #pragma unroll
    for (int nj = 0; nj < 4; ++nj)
      #pragma unroll
      for (int ks = 0; ks < 2; ++ks) {
        bf16x8 kf = *(const bf16x8*)(Kg + (long)(k0 + nj * 16 + l15) * 64 + ks * 32 + l4 * 8);
        sacc[nj] = __builtin_amdgcn_mfma_f32_16x16x32_bf16(qf[ks], kf, sacc[nj], 0, 0, 0);
      }

    // online softmax over 16-lane row groups
    float fsc[4];
    float pv_[4][4];
    #pragma unroll
    for (int i = 0; i < 4; ++i) {
      float sv[4];
      float vm = -1e30f;
      #pragma unroll
      for (int nj = 0; nj < 4; ++nj) {
        float bias = biasT[bko[i][nj]];
        float s = fmaf(sacc[nj][i], 0.125f, bias);
        s = vmask[nj] ? s : -1e30f;
        sv[nj] = s;
        vm = fmaxf(vm, s);
      }
      vm = fmaxf(vm, __shfl_xor(vm, 1));
      vm = fmaxf(vm, __shfl_xor(vm, 2));
      vm = fmaxf(vm, __shfl_xor(vm, 4));
      vm = fmaxf(vm, __shfl_xor(vm, 8));
      float mo = mrun[i];
      float mn = fmaxf(mo, vm);
      float f = __expf(mo - mn);
      float ps = 0.f;
      #pragma unroll
      for (int nj = 0; nj < 4; ++nj) {
        float p = __expf(sv[nj] - mn);
        pv_[i][nj] = p;
        ps += p;
      }
      ps += __shfl_xor(ps, 1);
      ps += __shfl_xor(ps, 2);
      ps += __shfl_xor(ps, 4);
      ps += __shfl_xor(ps, 8);
      lrun[i] = lrun[i] * f + ps;
      mrun[i] = mn;
      fsc[i] = f;
    }
    #pragma unroll
    for (int dj = 0; dj < 4; ++dj)
      #pragma unroll
      for (int i = 0; i < 4; ++i) oacc[dj][i] *= fsc[i];

    // P -> wave-private LDS (transpose to MFMA A layout), swizzled
    #pragma unroll
    for (int i = 0; i < 4; ++i) {
      int prow = (l4 << 2) + i;
      #pragma unroll
      for (int nj = 0; nj < 4; ++nj) {
        int pcolb = (nj * 16 + l15) * 2;
        *(unsigned short*)((char*)Pw + swz128(prow, pcolb)) = f2bf(pv_[i][nj]);
      }
    }
    bf16x8 pf[2];
    #pragma unroll
    for (int ks = 0; ks < 2; ++ks)
      pf[ks] = *(const bf16x8*)((const char*)Pw + swz128(l15, ks * 64 + l4 * 16));

    // O += P V from global V^T fragments
    #pragma unroll
    for (int dj = 0; dj < 4; ++dj)
      #pragma unroll
      for (int ks = 0; ks < 2; ++ks) {
        bf16x8 vf = *(const bf16x8*)(Vg + (long)(dj * 16 + l15) * 1024 + k0 + ks * 32 + l4 * 8);
        oacc[dj] = __builtin_amdgcn_mfma_f32_16x16x32_bf16(pf[ks], vf, oacc[dj], 0, 0, 0);
      }
  }

  // key-half merge: waves 4..7 publish partials, waves 0..3 combine + store
  if (w >= 4) {
    #pragma unroll
    for (int dj = 0; dj < 4; ++dj)
      #pragma unroll
      for (int i = 0; i < 4; ++i)
        O2[w - 4][(l4 << 2) + i][dj * 16 + l15] = oacc[dj][i];
    if (l15 == 0) {
      #pragma unroll
      for (int i = 0; i < 4; ++i) {
        M2[w - 4][(l4 << 2) + i] = mrun[i];
        L2s[w - 4][(l4 << 2) + i] = lrun[i];
      }
    }
  }
  __syncthreads();
  if (w < 4) {
    float fs1[4], fs2[4];
    #pragma unroll
    for (int i = 0; i < 4; ++i) {
      int row = (l4 << 2) + i;
      float m2 = M2[w][row], l2 = L2s[w][row];
      float mn = fmaxf(mrun[i], m2);
      float f1 = __expf(mrun[i] - mn);
      float f2 = __expf(m2 - mn);
      float linv = 1.f / (lrun[i] * f1 + l2 * f2);
      fs1[i] = f1 * linv;
      fs2[i] = f2 * linv;
    }
    #pragma unroll
    for (int dj = 0; dj < 4; ++dj)
      #pragma unroll
      for (int i = 0; i < 4; ++i) {
        int row = (l4 << 2) + i;
        int gq = qw + row;
        int dd = dj * 16 + l15;
        float o = oacc[dj][i] * fs1[i] + O2[w][row][dd] * fs2[i];
        AO[((long)((b << 10) + gq)) * 512 + h * 64 + dd] = f2bf(o);
      }
  }
}

// ---------------- output projection: out = AO @ Wo^T + bo (fp32 out) ------------
__global__ __launch_bounds__(256)
void k_gemm_out(const unsigned short* __restrict__ AO, const unsigned short* __restrict__ WO,
                const float* __restrict__ bo, float* __restrict__ out)
{
  __shared__ unsigned short ldsA[128 * 32];
  __shared__ unsigned short ldsB[64 * 32];
  int m0 = blockIdx.x * 128, n0 = blockIdx.y * 64;
  f32x4 acc[4][2];
  gemm_core64(AO, WO, m0, n0, ldsA, ldsB, acc);

  const int t = threadIdx.x, lane = t & 63, w = t >> 6;
  const int wm = (w >> 1) << 6, wn = (w & 1) << 5;
  const int l15 = lane & 15, l4 = lane >> 4;
  #pragma unroll
  for (int r = 0; r < 4; ++r)
    #pragma unroll
    for (int c = 0; c < 2; ++c)
      #pragma unroll
      for (int i = 0; i < 4; ++i) {
        int m = m0 + wm + r * 16 + (l4 << 2) + i;
        int n = n0 + wn + c * 16 + l15;
        out[(long)m * 512 + n] = acc[r][c][i] + bo[n];
      }
}

// ---------------- launch ---------------------------------------------------------
extern "C" void kernel_launch(void* const* d_in, const int* in_sizes, int n_in,
                              void* d_out, int out_size, void* d_ws, size_t ws_size,
                              hipStream_t stream) {
  const float* q      = (const float*)d_in[0];
  const float* k      = (const float*)d_in[1];
  const float* v      = (const float*)d_in[2];
  const float* coords = (const float*)d_in[3];
  const int*   mask   = (const int*)d_in[4];
  const float* Wq     = (const float*)d_in[5];
  const float* bq     = (const float*)d_in[6];
  const float* Wk     = (const float*)d_in[7];
  const float* bk     = (const float*)d_in[8];
  const float* Wv     = (const float*)d_in[9];
  const float* bv     = (const float*)d_in[10];
  const float* Wo     = (const float*)d_in[11];
  const float* bo     = (const float*)d_in[12];
  const float* rpe_x  = (const float*)d_in[13];
  const float* rpe_y  = (const float*)d_in[14];
  float* out = (float*)d_out;

  unsigned short* WQB  = (unsigned short*)d_ws;
  unsigned short* WKB  = WQB + 262144;
  unsigned short* WVB  = WKB + 262144;
  unsigned short* WOB  = WVB + 262144;
  unsigned short* XQ   = WOB + 262144;   // 3x2097152; dead after proj
  unsigned short* XK   = XQ + 2097152;
  unsigned short* XV   = XK + 2097152;
  unsigned short* QP   = XV + 2097152;
  unsigned short* KP   = QP + 2097152;
  unsigned short* VTMP = KP + 2097152;
  unsigned short* KC   = VTMP + 2097152;
  unsigned short* VCT  = KC + 2097152;
  unsigned short* AO   = VCT + 2097152;
  int* idxp            = (int*)(AO + 2097152);   // 4096 ints
  int* cntp            = idxp + 4096;            // 4 ints
  unsigned short* BUKC = XQ;   // alias: written after proj consumed XQ..XV

  k_cvt_all<<<dim3(3584), dim3(256), 0, stream>>>(q, k, v, Wq, Wk, Wv, Wo,
                                                  XQ, XK, XV, WQB, WKB, WVB, WOB);
  k_scan<<<dim3(4), dim3(1024), 0, stream>>>(mask, idxp, cntp);
  k_gemm_proj<<<dim3(32, 8, 3), dim3(256), 0, stream>>>(XQ, XK, XV, WQB, WKB, WVB,
                                                        bq, bk, bv, QP, KP, VTMP);
  k_gatherKV<<<dim3(16, 32), dim3(256), 0, stream>>>(KP, VTMP, idxp, cntp, KC, VCT);
  k_buckets_c<<<dim3(4096, 4), dim3(256), 0, stream>>>(coords, idxp, cntp, BUKC);
  k_attn<<<dim3(512), dim3(512), 0, stream>>>(QP, KC, VCT, BUKC, cntp,
                                              rpe_x, rpe_y, AO);
  k_gemm_out<<<dim3(32, 8), dim3(256), 0, stream>>>(AO, WOB, bo, out);
}

// Round 6
// 174.432 us; speedup vs baseline: 1.0443x; 1.0443x over previous
//
#include <hip/hip_runtime.h>
#include <hip/hip_bf16.h>

// B=4, G=1024, D=512, H=8, dh=64. NUM_BUCKETS=32, MAX_DIST=128, base=2.
typedef __attribute__((ext_vector_type(8))) short bf16x8;
typedef __attribute__((ext_vector_type(4))) float f32x4;

__device__ __forceinline__ unsigned short f2bf(float x) {
  union { __hip_bfloat16 h; unsigned short u; } cv;
  cv.h = __float2bfloat16(x);
  return cv.u;
}

__device__ __forceinline__ void gload16(const void* g, void* l) {
  __builtin_amdgcn_global_load_lds(
      (const __attribute__((address_space(1))) unsigned int*)g,
      (__attribute__((address_space(3))) unsigned int*)l, 16, 0, 0);
}

// swizzled byte offset for 128B-row LDS tiles
__device__ __forceinline__ int swz128(int row, int colb) {
  return row * 128 + (colb ^ ((row & 7) << 4));
}

// ---------------- fused fp32->bf16 conversion + mask prefix-scan ----------------
__global__ __launch_bounds__(256)
void k_cvt_scan(const float* __restrict__ q, const float* __restrict__ k,
                const float* __restrict__ v, const float* __restrict__ Wq,
                const float* __restrict__ Wk, const float* __restrict__ Wv,
                const float* __restrict__ Wo, const int* __restrict__ mask,
                unsigned short* __restrict__ XQ, unsigned short* __restrict__ XK,
                unsigned short* __restrict__ XV, unsigned short* __restrict__ WQB,
                unsigned short* __restrict__ WKB, unsigned short* __restrict__ WVB,
                unsigned short* __restrict__ WOB,
                int* __restrict__ idx, int* __restrict__ cnt)
{
  __shared__ int wsum[4];
  int bid = blockIdx.x;
  if (bid >= 3584) {
    // per-batch mask compaction: 256 threads, 4 contiguous elems each
    int b = bid - 3584;
    int tdx = threadIdx.x;
    int lane = tdx & 63, w = tdx >> 6;
    int base = tdx * 4;
    int m[4]; int s = 0;
    #pragma unroll
    for (int j = 0; j < 4; ++j) { m[j] = mask[(b << 10) + base + j]; s += m[j]; }
    int x = s;
    #pragma unroll
    for (int d = 1; d < 64; d <<= 1) {
      int vv = __shfl_up(x, d);
      if (lane >= d) x += vv;
    }
    if (lane == 63) wsum[w] = x;
    __syncthreads();
    int off = 0;
    #pragma unroll
    for (int ww = 0; ww < 4; ++ww) off += (ww < w) ? wsum[ww] : 0;
    int pos = off + x - s;
    #pragma unroll
    for (int j = 0; j < 4; ++j) if (m[j]) idx[(b << 10) + pos++] = base + j;
    if (tdx == 255) cnt[b] = off + x;
    return;
  }
  long i = ((long)bid * 256 + threadIdx.x) * 8;
  const float* s; unsigned short* d; long off;
  if (i < 2097152)      { s = q; d = XQ; off = i; }
  else if (i < 4194304) { s = k; d = XK; off = i - 2097152; }
  else if (i < 6291456) { s = v; d = XV; off = i - 4194304; }
  else {
    long j = i - 6291456;
    int wsel = (int)(j >> 18);
    off = j & 262143;
    s = wsel == 0 ? Wq : wsel == 1 ? Wk : wsel == 2 ? Wv : Wo;
    d = wsel == 0 ? WQB : wsel == 1 ? WKB : wsel == 2 ? WVB : WOB;
  }
  float4 a = *(const float4*)(s + off);
  float4 bb = *(const float4*)(s + off + 4);
  bf16x8 o;
  o[0] = (short)f2bf(a.x);  o[1] = (short)f2bf(a.y);
  o[2] = (short)f2bf(a.z);  o[3] = (short)f2bf(a.w);
  o[4] = (short)f2bf(bb.x); o[5] = (short)f2bf(bb.y);
  o[6] = (short)f2bf(bb.z); o[7] = (short)f2bf(bb.w);
  *(bf16x8*)(d + off) = o;
}

// ---------------- bucket helper -------------------------------------------------
__device__ __forceinline__ int rbucket(float dd) {
  float ad = fabsf(dd);
  float n = fminf(fmaxf(ad, 1e-6f), 128.0f);
  int li = (int)floorf(logf(n) * 1.4426950408889634f);
  li = li < 0 ? 0 : (li > 31 ? 31 : li);
  int s = (dd > 0.f) ? 1 : ((dd < 0.f) ? -1 : 0);
  return li * s + 31;
}

// ---------------- fused K/V gather + compacted bucket table ---------------------
// blocks [0,512): gather compacted K rows + transposed V; [512,16896): buckets
__global__ __launch_bounds__(256)
void k_gather_buckets(const unsigned short* __restrict__ KP,
                      const unsigned short* __restrict__ VTMP,
                      const float* __restrict__ coords,
                      const int* __restrict__ idx, const int* __restrict__ cnt,
                      unsigned short* __restrict__ KC, unsigned short* __restrict__ VCT,
                      unsigned short* __restrict__ buk)
{
  __shared__ unsigned short tile[64][68];
  __shared__ int lidx[64];
  int t = threadIdx.x;
  if (blockIdx.x < 512) {
    int gid = blockIdx.x;
    int bh = gid & 31, b = bh >> 3;
    int cn = cnt[b];
    int ck0 = (gid >> 5) << 6;
    if (ck0 >= cn) return;
    if (t < 64) lidx[t] = idx[(b << 10) + min(ck0 + t, cn - 1)];
    __syncthreads();
    int r = t >> 2, qd = t & 3;
    long srcrow = ((long)(bh << 10) + lidx[r]) * 64;
    long dstrow = ((long)(bh << 10) + ck0 + r) * 64;
    uint4 kv0 = *(const uint4*)(KP + srcrow + qd * 16);
    uint4 kv1 = *(const uint4*)(KP + srcrow + qd * 16 + 8);
    *(uint4*)(KC + dstrow + qd * 16) = kv0;
    *(uint4*)(KC + dstrow + qd * 16 + 8) = kv1;
    const uint2* vsrc = (const uint2*)(VTMP + srcrow + qd * 16);
    #pragma unroll
    for (int s = 0; s < 4; ++s)
      *(uint2*)(&tile[r][qd * 16 + s * 4]) = vsrc[s];
    __syncthreads();
    #pragma unroll
    for (int it = 0; it < 16; ++it) {
      int d = it * 4 + (t >> 6);
      int ck = t & 63;
      VCT[((long)(bh << 6) + d) * 1024 + ck0 + ck] = tile[ck][d];
    }
    return;
  }
  // bucket table: combined idx bx*63+by, permuted within 64-key chunk
  int bid2 = blockIdx.x - 512;
  int b = bid2 >> 12;
  int f = ((bid2 & 4095) << 8) + t;   // q*1024 + ck
  int qi = f >> 10, ck = f & 1023;
  int cn = cnt[b];
  int cnp = (cn + 63) & ~63;
  if (ck >= cnp) return;
  int pos = (ck & ~63) | ((ck & 15) << 2) | ((ck >> 4) & 3);
  unsigned short val = 0;
  if (ck < cn) {
    int ki = idx[(b << 10) + ck];
    const float* cb = coords + (b << 11);
    float dx = cb[qi * 2]     - cb[ki * 2];
    float dy = cb[qi * 2 + 1] - cb[ki * 2 + 1];
    val = (unsigned short)(rbucket(dx) * 63 + rbucket(dy));
  }
  buk[((long)(b << 10) + qi) * 1024 + pos] = val;
}

// ---------------- GEMM core: C = A(M,512) @ Bw(N,512)^T, 128x64 tile, 4 waves ---
__device__ __forceinline__ void gemm_core64(
    const unsigned short* __restrict__ A, const unsigned short* __restrict__ Bw,
    int m0, int n0, unsigned short* ldsA, unsigned short* ldsB, f32x4 acc[4][2])
{
  const int t = threadIdx.x;
  const int lane = t & 63;
  const int w = t >> 6;
  const int wm = (w >> 1) << 6;
  const int wn = (w & 1) << 5;
  const int l15 = lane & 15;
  const int l4 = lane >> 4;
  const f32x4 fz = {0.f, 0.f, 0.f, 0.f};

  #pragma unroll
  for (int r = 0; r < 4; ++r)
    #pragma unroll
    for (int c = 0; c < 2; ++c) acc[r][c] = fz;

  for (int k0 = 0; k0 < 512; k0 += 32) {
    #pragma unroll
    for (int rr = 0; rr < 2; ++rr) {
      int c = rr * 256 + t;
      int row = c >> 2, cc = c & 3;
      gload16(A + (m0 + row) * 512 + k0 + cc * 8, (char*)ldsA + c * 16);
    }
    {
      int c = t;
      int row = c >> 2, cc = c & 3;
      gload16(Bw + (n0 + row) * 512 + k0 + cc * 8, (char*)ldsB + c * 16);
    }
    __syncthreads();
    bf16x8 af[4], bfr[2];
    #pragma unroll
    for (int r = 0; r < 4; ++r)
      af[r] = *(const bf16x8*)((const char*)ldsA + (wm + r * 16 + l15) * 64 + l4 * 16);
    #pragma unroll
    for (int c = 0; c < 2; ++c)
      bfr[c] = *(const bf16x8*)((const char*)ldsB + (wn + c * 16 + l15) * 64 + l4 * 16);
    #pragma unroll
    for (int r = 0; r < 4; ++r)
      #pragma unroll
      for (int c = 0; c < 2; ++c)
        acc[r][c] = __builtin_amdgcn_mfma_f32_16x16x32_bf16(af[r], bfr[c], acc[r][c], 0, 0, 0);
    __syncthreads();
  }
}

// ---------------- Q/K/V projections -> (B,H,G,64) bf16 --------------------------
__global__ __launch_bounds__(256)
void k_gemm_proj(const unsigned short* __restrict__ XQ, const unsigned short* __restrict__ XK,
                 const unsigned short* __restrict__ XV, const unsigned short* __restrict__ WQ,
                 const unsigned short* __restrict__ WK, const unsigned short* __restrict__ WV,
                 const float* __restrict__ bq, const float* __restrict__ bk,
                 const float* __restrict__ bv,
                 unsigned short* __restrict__ QP, unsigned short* __restrict__ KP,
                 unsigned short* __restrict__ VT)
{
  __shared__ unsigned short ldsA[128 * 32];
  __shared__ unsigned short ldsB[64 * 32];
  int z = blockIdx.z;
  const unsigned short* A = z == 0 ? XQ : z == 1 ? XK : XV;
  const unsigned short* W = z == 0 ? WQ : z == 1 ? WK : WV;
  const float* bias = z == 0 ? bq : z == 1 ? bk : bv;
  unsigned short* dst = z == 0 ? QP : z == 1 ? KP : VT;
  int m0 = blockIdx.x * 128, n0 = blockIdx.y * 64;
  f32x4 acc[4][2];
  gemm_core64(A, W, m0, n0, ldsA, ldsB, acc);

  const int t = threadIdx.x, lane = t & 63, w = t >> 6;
  const int wm = (w >> 1) << 6, wn = (w & 1) << 5;
  const int l15 = lane & 15, l4 = lane >> 4;
  #pragma unroll
  for (int r = 0; r < 4; ++r)
    #pragma unroll
    for (int c = 0; c < 2; ++c)
      #pragma unroll
      for (int i = 0; i < 4; ++i) {
        int m = m0 + wm + r * 16 + (l4 << 2) + i;   // token
        int n = n0 + wn + c * 16 + l15;             // channel
        float y = acc[r][c][i] + bias[n];
        int b = m >> 10, g = m & 1023, hh = n >> 6, dd = n & 63;
        dst[((((b << 3) + hh) << 10) + g) * 64 + dd] = f2bf(y);
      }
}

// ---------------- flash attention: static-max softmax + K/bucket reg prefetch ---
// grid 512 x 256. Wave owns 16 q rows, iterates all compacted key tiles.
#define ATTN_STEP(K0, KF, BF)                                                     \
  do {                                                                            \
    const int k0_ = (K0);                                                         \
    bf16x8 vloc[8];                                                               \
    _Pragma("unroll") for (int dj = 0; dj < 4; ++dj)                              \
      _Pragma("unroll") for (int ks = 0; ks < 2; ++ks)                            \
        vloc[dj*2+ks] = *(const bf16x8*)(Vg + (long)(dj*16 + l15)*1024 + k0_ + ks*32 + l4*8); \
    f32x4 sacc[4] = {fz, fz, fz, fz};                                             \
    _Pragma("unroll") for (int nj = 0; nj < 4; ++nj)                              \
      _Pragma("unroll") for (int ks = 0; ks < 2; ++ks)                            \
        sacc[nj] = __builtin_amdgcn_mfma_f32_16x16x32_bf16(qf[ks], KF[nj*2+ks], sacc[nj], 0, 0, 0); \
    int vm0 = (k0_ + l15) < cn, vm1 = (k0_ + 16 + l15) < cn;                      \
    int vm2 = (k0_ + 32 + l15) < cn, vm3 = (k0_ + 48 + l15) < cn;                 \
    _Pragma("unroll") for (int i = 0; i < 4; ++i) {                               \
      unsigned bvx = BF[i].x, bvy = BF[i].y;                                      \
      float p0 = vm0 ? exp2f(fmaf(sacc[0][i], SCL, biasT[bvx & 0xffff])) : 0.f;   \
      float p1 = vm1 ? exp2f(fmaf(sacc[1][i], SCL, biasT[bvx >> 16])) : 0.f;      \
      float p2 = vm2 ? exp2f(fmaf(sacc[2][i], SCL, biasT[bvy & 0xffff])) : 0.f;   \
      float p3 = vm3 ? exp2f(fmaf(sacc[3][i], SCL, biasT[bvy >> 16])) : 0.f;      \
      lsum[i] += (p0 + p1) + (p2 + p3);                                           \
      int prow = (l4 << 2) + i;                                                   \
      *(unsigned short*)((char*)Pw + swz128(prow, (l15) * 2))      = f2bf(p0);    \
      *(unsigned short*)((char*)Pw + swz128(prow, (16 + l15) * 2)) = f2bf(p1);    \
      *(unsigned short*)((char*)Pw + swz128(prow, (32 + l15) * 2)) = f2bf(p2);    \
      *(unsigned short*)((char*)Pw + swz128(prow, (48 + l15) * 2)) = f2bf(p3);    \
    }                                                                             \
    bf16x8 pf[2];                                                                 \
    _Pragma("unroll") for (int ks = 0; ks < 2; ++ks)                              \
      pf[ks] = *(const bf16x8*)((const char*)Pw + swz128(l15, ks * 64 + l4 * 16)); \
    _Pragma("unroll") for (int dj = 0; dj < 4; ++dj)                              \
      _Pragma("unroll") for (int ks = 0; ks < 2; ++ks)                            \
        oacc[dj] = __builtin_amdgcn_mfma_f32_16x16x32_bf16(pf[ks], vloc[dj*2+ks], oacc[dj], 0, 0, 0); \
  } while (0)

#define ATTN_LDK(K0, DST)                                                         \
  do {                                                                            \
    const int kk_ = (K0);                                                         \
    _Pragma("unroll") for (int nj = 0; nj < 4; ++nj)                              \
      _Pragma("unroll") for (int ks = 0; ks < 2; ++ks)                            \
        DST[nj*2+ks] = *(const bf16x8*)(Kg + (long)(kk_ + nj*16 + l15)*64 + ks*32 + l4*8); \
  } while (0)

#define ATTN_LDB(K0, DST)                                                         \
  do {                                                                            \
    const int kk_ = (K0);                                                         \
    _Pragma("unroll") for (int i = 0; i < 4; ++i)                                 \
      DST[i] = *(const uint2*)(bukb + (long)((l4 << 2) + i) * 1024 + kk_ + (l15 << 2)); \
  } while (0)

__global__ __launch_bounds__(256)
void k_attn(const unsigned short* __restrict__ QP, const unsigned short* __restrict__ KC,
            const unsigned short* __restrict__ VCT, const unsigned short* __restrict__ BUKC,
            const int* __restrict__ cnt, const float* __restrict__ rpe_x,
            const float* __restrict__ rpe_y, unsigned short* __restrict__ AO)
{
  __shared__ float biasT[3969];            // pre-scaled: (rx+ry-20)*log2e
  __shared__ unsigned short Ps[4][1024];   // per-wave P-transpose, swizzled

  const int t = threadIdx.x;
  const int lane = t & 63;
  const int w = t >> 6;
  const int l15 = lane & 15;
  const int l4 = lane >> 4;
  const f32x4 fz = {0.f, 0.f, 0.f, 0.f};
  const float SCL = 0.18033688f;           // log2e / 8

  // XCD swizzle: each XCD handles one (batch, q-half)
  int g = blockIdx.x;
  int xcd = g & 7, slot = g >> 3;
  int b = xcd >> 1;
  int qb = ((xcd & 1) << 3) | (slot & 7);
  int h = slot >> 3;
  int bh = (b << 3) | h;
  int qw = (qb << 6) | (w << 4);

  for (int j = t; j < 3969; j += 256) {
    int bx = (int)(j * 0.015873017f);      // j/63 (verified exact for j<3969)
    int by = j - bx * 63;
    biasT[j] = (rpe_x[bx * 8 + h] + rpe_y[by * 8 + h] - 20.0f) * 1.4426950408889634f;
  }
  __syncthreads();

  const unsigned short* Qg = QP + ((long)(bh << 10) + qw) * 64;
  bf16x8 qf[2];
  #pragma unroll
  for (int ks = 0; ks < 2; ++ks)
    qf[ks] = *(const bf16x8*)(Qg + (long)l15 * 64 + ks * 32 + l4 * 8);

  const int cn = cnt[b];
  const int nkt = (cn + 63) >> 6;
  const unsigned short* Kg = KC + ((long)(bh << 10)) * 64;
  const unsigned short* Vg = VCT + ((long)(bh << 6)) * 1024;
  const unsigned short* bukb = BUKC + ((long)(b << 10) + qw) * 1024;
  unsigned short* Pw = &Ps[w][0];

  float lsum[4] = {0.f, 0.f, 0.f, 0.f};
  f32x4 oacc[4];
  #pragma unroll
  for (int dj = 0; dj < 4; ++dj) oacc[dj] = fz;

  bf16x8 kA[8], kB[8];
  uint2 bA[4], bB[4];
  ATTN_LDK(0, kA); ATTN_LDB(0, bA);
  for (int kt = 0; kt < nkt; kt += 2) {
    int k1 = min(kt + 1, nkt - 1) << 6;
    ATTN_LDK(k1, kB); ATTN_LDB(k1, bB);
    ATTN_STEP(kt << 6, kA, bA);
    if (kt + 1 < nkt) {
      int k2 = min(kt + 2, nkt - 1) << 6;
      ATTN_LDK(k2, kA); ATTN_LDB(k2, bA);
      ATTN_STEP(k1, kB, bB);
    }
  }

  // row-sum reduce (once, not per tile) + normalize + store
  #pragma unroll
  for (int i = 0; i < 4; ++i) {
    lsum[i] += __shfl_xor(lsum[i], 1);
    lsum[i] += __shfl_xor(lsum[i], 2);
    lsum[i] += __shfl_xor(lsum[i], 4);
    lsum[i] += __shfl_xor(lsum[i], 8);
    lsum[i] = 1.f / lsum[i];
  }
  #pragma unroll
  for (int dj = 0; dj < 4; ++dj)
    #pragma unroll
    for (int i = 0; i < 4; ++i) {
      int gq = qw + (l4 << 2) + i;
      int dd = dj * 16 + l15;
      AO[((long)((b << 10) + gq)) * 512 + h * 64 + dd] = f2bf(oacc[dj][i] * lsum[i]);
    }
}

// ---------------- output projection: out = AO @ Wo^T + bo (fp32 out) ------------
__global__ __launch_bounds__(256)
void k_gemm_out(const unsigned short* __restrict__ AO, const unsigned short* __restrict__ WO,
                const float* __restrict__ bo, float* __restrict__ out)
{
  __shared__ unsigned short ldsA[128 * 32];
  __shared__ unsigned short ldsB[64 * 32];
  int m0 = blockIdx.x * 128, n0 = blockIdx.y * 64;
  f32x4 acc[4][2];
  gemm_core64(AO, WO, m0, n0, ldsA, ldsB, acc);

  const int t = threadIdx.x, lane = t & 63, w = t >> 6;
  const int wm = (w >> 1) << 6, wn = (w & 1) << 5;
  const int l15 = lane & 15, l4 = lane >> 4;
  #pragma unroll
  for (int r = 0; r < 4; ++r)
    #pragma unroll
    for (int c = 0; c < 2; ++c)
      #pragma unroll
      for (int i = 0; i < 4; ++i) {
        int m = m0 + wm + r * 16 + (l4 << 2) + i;
        int n = n0 + wn + c * 16 + l15;
        out[(long)m * 512 + n] = acc[r][c][i] + bo[n];
      }
}

// ---------------- launch ---------------------------------------------------------
extern "C" void kernel_launch(void* const* d_in, const int* in_sizes, int n_in,
                              void* d_out, int out_size, void* d_ws, size_t ws_size,
                              hipStream_t stream) {
  const float* q      = (const float*)d_in[0];
  const float* k      = (const float*)d_in[1];
  const float* v      = (const float*)d_in[2];
  const float* coords = (const float*)d_in[3];
  const int*   mask   = (const int*)d_in[4];
  const float* Wq     = (const float*)d_in[5];
  const float* bq     = (const float*)d_in[6];
  const float* Wk     = (const float*)d_in[7];
  const float* bk     = (const float*)d_in[8];
  const float* Wv     = (const float*)d_in[9];
  const float* bv     = (const float*)d_in[10];
  const float* Wo     = (const float*)d_in[11];
  const float* bo     = (const float*)d_in[12];
  const float* rpe_x  = (const float*)d_in[13];
  const float* rpe_y  = (const float*)d_in[14];
  float* out = (float*)d_out;

  unsigned short* WQB  = (unsigned short*)d_ws;
  unsigned short* WKB  = WQB + 262144;
  unsigned short* WVB  = WKB + 262144;
  unsigned short* WOB  = WVB + 262144;
  unsigned short* XQ   = WOB + 262144;   // 3x2097152; dead after proj
  unsigned short* XK   = XQ + 2097152;
  unsigned short* XV   = XK + 2097152;
  unsigned short* QP   = XV + 2097152;
  unsigned short* KP   = QP + 2097152;
  unsigned short* VTMP = KP + 2097152;
  unsigned short* KC   = VTMP + 2097152;
  unsigned short* VCT  = KC + 2097152;
  unsigned short* AO   = VCT + 2097152;
  int* idxp            = (int*)(AO + 2097152);   // 4096 ints
  int* cntp            = idxp + 4096;            // 4 ints
  unsigned short* BUKC = XQ;   // alias: written after proj consumed XQ..XV

  k_cvt_scan<<<dim3(3588), dim3(256), 0, stream>>>(q, k, v, Wq, Wk, Wv, Wo, mask,
                                                   XQ, XK, XV, WQB, WKB, WVB, WOB,
                                                   idxp, cntp);
  k_gemm_proj<<<dim3(32, 8, 3), dim3(256), 0, stream>>>(XQ, XK, XV, WQB, WKB, WVB,
                                                        bq, bk, bv, QP, KP, VTMP);
  k_gather_buckets<<<dim3(16896), dim3(256), 0, stream>>>(KP, VTMP, coords, idxp, cntp,
                                                          KC, VCT, BUKC);
  k_attn<<<dim3(512), dim3(256), 0, stream>>>(QP, KC, VCT, BUKC, cntp,
                                              rpe_x, rpe_y, AO);
  k_gemm_out<<<dim3(32, 8), dim3(256), 0, stream>>>(AO, WOB, bo, out);
}

// Round 7
// 169.844 us; speedup vs baseline: 1.0725x; 1.0270x over previous
//
#include <hip/hip_runtime.h>
#include <hip/hip_bf16.h>

// B=4, G=1024, D=512, H=8, dh=64. NUM_BUCKETS=32, MAX_DIST=128, base=2.
typedef __attribute__((ext_vector_type(8))) short bf16x8;
typedef __attribute__((ext_vector_type(4))) float f32x4;
typedef __attribute__((ext_vector_type(16))) float f32x16;

__device__ __forceinline__ unsigned short f2bf(float x) {
  union { __hip_bfloat16 h; unsigned short u; } cv;
  cv.h = __float2bfloat16(x);
  return cv.u;
}

__device__ __forceinline__ void gload16(const void* g, void* l) {
  __builtin_amdgcn_global_load_lds(
      (const __attribute__((address_space(1))) unsigned int*)g,
      (__attribute__((address_space(3))) unsigned int*)l, 16, 0, 0);
}

// exchange a.hi-lanes with b.lo-lanes (gfx950 cross-half primitive)
__device__ __forceinline__ void pl32swap(unsigned &a, unsigned &b) {
  asm volatile("v_permlane32_swap_b32 %0, %1" : "+v"(a), "+v"(b));
}

// ---------------- fused fp32->bf16 conversion + mask prefix-scan ----------------
__global__ __launch_bounds__(256)
void k_cvt_scan(const float* __restrict__ q, const float* __restrict__ k,
                const float* __restrict__ v, const float* __restrict__ Wq,
                const float* __restrict__ Wk, const float* __restrict__ Wv,
                const float* __restrict__ Wo, const int* __restrict__ mask,
                unsigned short* __restrict__ XQ, unsigned short* __restrict__ XK,
                unsigned short* __restrict__ XV, unsigned short* __restrict__ WQB,
                unsigned short* __restrict__ WKB, unsigned short* __restrict__ WVB,
                unsigned short* __restrict__ WOB,
                int* __restrict__ idx, int* __restrict__ cnt)
{
  __shared__ int wsum[4];
  int bid = blockIdx.x;
  if (bid >= 3584) {
    int b = bid - 3584;
    int tdx = threadIdx.x;
    int lane = tdx & 63, w = tdx >> 6;
    int base = tdx * 4;
    int m[4]; int s = 0;
    #pragma unroll
    for (int j = 0; j < 4; ++j) { m[j] = mask[(b << 10) + base + j]; s += m[j]; }
    int x = s;
    #pragma unroll
    for (int d = 1; d < 64; d <<= 1) {
      int vv = __shfl_up(x, d);
      if (lane >= d) x += vv;
    }
    if (lane == 63) wsum[w] = x;
    __syncthreads();
    int off = 0;
    #pragma unroll
    for (int ww = 0; ww < 4; ++ww) off += (ww < w) ? wsum[ww] : 0;
    int pos = off + x - s;
    #pragma unroll
    for (int j = 0; j < 4; ++j) if (m[j]) idx[(b << 10) + pos++] = base + j;
    if (tdx == 255) cnt[b] = off + x;
    return;
  }
  long i = ((long)bid * 256 + threadIdx.x) * 8;
  const float* s; unsigned short* d; long off;
  if (i < 2097152)      { s = q; d = XQ; off = i; }
  else if (i < 4194304) { s = k; d = XK; off = i - 2097152; }
  else if (i < 6291456) { s = v; d = XV; off = i - 4194304; }
  else {
    long j = i - 6291456;
    int wsel = (int)(j >> 18);
    off = j & 262143;
    s = wsel == 0 ? Wq : wsel == 1 ? Wk : wsel == 2 ? Wv : Wo;
    d = wsel == 0 ? WQB : wsel == 1 ? WKB : wsel == 2 ? WVB : WOB;
  }
  float4 a = *(const float4*)(s + off);
  float4 bb = *(const float4*)(s + off + 4);
  bf16x8 o;
  o[0] = (short)f2bf(a.x);  o[1] = (short)f2bf(a.y);
  o[2] = (short)f2bf(a.z);  o[3] = (short)f2bf(a.w);
  o[4] = (short)f2bf(bb.x); o[5] = (short)f2bf(bb.y);
  o[6] = (short)f2bf(bb.z); o[7] = (short)f2bf(bb.w);
  *(bf16x8*)(d + off) = o;
}

// ---------------- bucket helper -------------------------------------------------
__device__ __forceinline__ int rbucket(float dd) {
  float ad = fabsf(dd);
  float n = fminf(fmaxf(ad, 1e-6f), 128.0f);
  int li = (int)floorf(logf(n) * 1.4426950408889634f);
  li = li < 0 ? 0 : (li > 31 ? 31 : li);
  int s = (dd > 0.f) ? 1 : ((dd < 0.f) ? -1 : 0);
  return li * s + 31;
}

// ---------------- fused K/V gather + compacted bucket table ---------------------
// blocks [0,512): gather compacted K rows + transposed V; [512,16896): buckets.
// Buckets stored crow-permuted within each 32-key chunk so attn lane (q,hi)
// reads its 16 reg-ordered entries as 2x b128. Pad entries -> 3969 (pbT==0).
__global__ __launch_bounds__(256)
void k_gather_buckets(const unsigned short* __restrict__ KP,
                      const unsigned short* __restrict__ VTMP,
                      const float* __restrict__ coords,
                      const int* __restrict__ idx, const int* __restrict__ cnt,
                      unsigned short* __restrict__ KC, unsigned short* __restrict__ VCT,
                      unsigned short* __restrict__ buk)
{
  __shared__ unsigned short tile[64][68];
  __shared__ int lidx[64];
  int t = threadIdx.x;
  if (blockIdx.x < 512) {
    int gid = blockIdx.x;
    int bh = gid & 31, b = bh >> 3;
    int cn = cnt[b];
    int ck0 = (gid >> 5) << 6;
    if (ck0 >= cn) return;
    if (t < 64) lidx[t] = idx[(b << 10) + min(ck0 + t, cn - 1)];
    __syncthreads();
    int r = t >> 2, qd = t & 3;
    long srcrow = ((long)(bh << 10) + lidx[r]) * 64;
    long dstrow = ((long)(bh << 10) + ck0 + r) * 64;
    uint4 kv0 = *(const uint4*)(KP + srcrow + qd * 16);
    uint4 kv1 = *(const uint4*)(KP + srcrow + qd * 16 + 8);
    *(uint4*)(KC + dstrow + qd * 16) = kv0;
    *(uint4*)(KC + dstrow + qd * 16 + 8) = kv1;
    const uint2* vsrc = (const uint2*)(VTMP + srcrow + qd * 16);
    #pragma unroll
    for (int s = 0; s < 4; ++s)
      *(uint2*)(&tile[r][qd * 16 + s * 4]) = vsrc[s];
    __syncthreads();
    #pragma unroll
    for (int it = 0; it < 16; ++it) {
      int d = it * 4 + (t >> 6);
      int ck = t & 63;
      VCT[((long)(bh << 6) + d) * 1024 + ck0 + ck] = tile[ck][d];
    }
    return;
  }
  int bid2 = blockIdx.x - 512;
  int b = bid2 >> 12;
  int f = ((bid2 & 4095) << 8) + t;   // q*1024 + ck
  int qi = f >> 10, ck = f & 1023;
  int cn = cnt[b];
  int cnp = (cn + 63) & ~63;
  if (ck >= cnp) return;
  // crow permutation within 32-chunk: o = r + 16*hi, k = (r&3)+8*(r>>2)+4*hi
  int kq = ck & 31;
  int o = ((kq & 3) | ((kq >> 3) << 2)) + ((kq & 4) << 2);
  int pos = (ck & ~31) | o;
  unsigned short val = 3969;           // pad -> pbT[3969] = 0
  if (ck < cn) {
    int ki = idx[(b << 10) + ck];
    const float* cb = coords + (b << 11);
    float dx = cb[qi * 2]     - cb[ki * 2];
    float dy = cb[qi * 2 + 1] - cb[ki * 2 + 1];
    val = (unsigned short)(rbucket(dx) * 63 + rbucket(dy));
  }
  buk[((long)(b << 10) + qi) * 1024 + pos] = val;
}

// ---------------- GEMM core: C = A(M,512) @ Bw(N,512)^T, 128x64 tile, 4 waves ---
__device__ __forceinline__ void gemm_core64(
    const unsigned short* __restrict__ A, const unsigned short* __restrict__ Bw,
    int m0, int n0, unsigned short* ldsA, unsigned short* ldsB, f32x4 acc[4][2])
{
  const int t = threadIdx.x;
  const int lane = t & 63;
  const int w = t >> 6;
  const int wm = (w >> 1) << 6;
  const int wn = (w & 1) << 5;
  const int l15 = lane & 15;
  const int l4 = lane >> 4;
  const f32x4 fz = {0.f, 0.f, 0.f, 0.f};

  #pragma unroll
  for (int r = 0; r < 4; ++r)
    #pragma unroll
    for (int c = 0; c < 2; ++c) acc[r][c] = fz;

  for (int k0 = 0; k0 < 512; k0 += 32) {
    #pragma unroll
    for (int rr = 0; rr < 2; ++rr) {
      int c = rr * 256 + t;
      int row = c >> 2, cc = c & 3;
      gload16(A + (m0 + row) * 512 + k0 + cc * 8, (char*)ldsA + c * 16);
    }
    {
      int c = t;
      int row = c >> 2, cc = c & 3;
      gload16(Bw + (n0 + row) * 512 + k0 + cc * 8, (char*)ldsB + c * 16);
    }
    __syncthreads();
    bf16x8 af[4], bfr[2];
    #pragma unroll
    for (int r = 0; r < 4; ++r)
      af[r] = *(const bf16x8*)((const char*)ldsA + (wm + r * 16 + l15) * 64 + l4 * 16);
    #pragma unroll
    for (int c = 0; c < 2; ++c)
      bfr[c] = *(const bf16x8*)((const char*)ldsB + (wn + c * 16 + l15) * 64 + l4 * 16);
    #pragma unroll
    for (int r = 0; r < 4; ++r)
      #pragma unroll
      for (int c = 0; c < 2; ++c)
        acc[r][c] = __builtin_amdgcn_mfma_f32_16x16x32_bf16(af[r], bfr[c], acc[r][c], 0, 0, 0);
    __syncthreads();
  }
}

// ---------------- Q/K/V projections -> (B,H,G,64) bf16 --------------------------
__global__ __launch_bounds__(256)
void k_gemm_proj(const unsigned short* __restrict__ XQ, const unsigned short* __restrict__ XK,
                 const unsigned short* __restrict__ XV, const unsigned short* __restrict__ WQ,
                 const unsigned short* __restrict__ WK, const unsigned short* __restrict__ WV,
                 const float* __restrict__ bq, const float* __restrict__ bk,
                 const float* __restrict__ bv,
                 unsigned short* __restrict__ QP, unsigned short* __restrict__ KP,
                 unsigned short* __restrict__ VT)
{
  __shared__ unsigned short ldsA[128 * 32];
  __shared__ unsigned short ldsB[64 * 32];
  int z = blockIdx.z;
  const unsigned short* A = z == 0 ? XQ : z == 1 ? XK : XV;
  const unsigned short* W = z == 0 ? WQ : z == 1 ? WK : WV;
  const float* bias = z == 0 ? bq : z == 1 ? bk : bv;
  unsigned short* dst = z == 0 ? QP : z == 1 ? KP : VT;
  int m0 = blockIdx.x * 128, n0 = blockIdx.y * 64;
  f32x4 acc[4][2];
  gemm_core64(A, W, m0, n0, ldsA, ldsB, acc);

  const int t = threadIdx.x, lane = t & 63, w = t >> 6;
  const int wm = (w >> 1) << 6, wn = (w & 1) << 5;
  const int l15 = lane & 15, l4 = lane >> 4;
  #pragma unroll
  for (int r = 0; r < 4; ++r)
    #pragma unroll
    for (int c = 0; c < 2; ++c)
      #pragma unroll
      for (int i = 0; i < 4; ++i) {
        int m = m0 + wm + r * 16 + (l4 << 2) + i;   // token
        int n = n0 + wn + c * 16 + l15;             // channel
        float y = acc[r][c][i] + bias[n];
        int b = m >> 10, g = m & 1023, hh = n >> 6, dd = n & 63;
        dst[((((b << 3) + hh) << 10) + g) * 64 + dd] = f2bf(y);
      }
}

// ---------------- flash attention: 32x32 swapped-QK, in-register softmax --------
// grid 1024 x 256. Block = 32 q rows of one (b,h); 4 waves = key quarters.
// S^T = mfma(K, Q^T): lane owns q=lane&31; rows k=crow(r,hi). p stays in regs;
// PV as O^T = mfma(V^T, P) with P rebuilt via bf16-pack + permlane32_swap.
// Static-max softmax (m=20 folded into exp-table pbT); merge = pure add.
__global__ __launch_bounds__(256)
void k_attn(const unsigned short* __restrict__ QP, const unsigned short* __restrict__ KC,
            const unsigned short* __restrict__ VCT, const unsigned short* __restrict__ BUKP,
            const int* __restrict__ cnt, const float* __restrict__ rpe_x,
            const float* __restrict__ rpe_y, unsigned short* __restrict__ AO)
{
  __shared__ float smem[8320];               // 33.3KB: pbT[3970] aliases Omrg[4][32][64]
  float* pbT = smem;
  float (*Omrg)[32][64] = (float(*)[32][64])smem;
  float* Lmrg = smem + 8192;                 // [4][32]

  const int t = threadIdx.x;
  const int lane = t & 63;
  const int w = t >> 6;
  const int ql = lane & 31;
  const int hi = lane >> 5;
  const float SCL = 0.18033688f;             // log2e / 8

  int g = blockIdx.x;
  int qb = g & 31, b = (g >> 5) & 3, h = g >> 7;   // same (b,qb) -> same XCD
  int bh = (b << 3) | h;
  int q0 = qb << 5;

  // exp-bias table: pbT[j] = 2^(bias*log2e - 20*log2e); pad entry 3969 -> 0
  for (int j = t; j < 3970; j += 256) {
    int bx = (int)(j * 0.015873017f);
    int by = j - bx * 63;
    float vv = 0.f;
    if (j < 3969)
      vv = exp2f((rpe_x[bx * 8 + h] + rpe_y[by * 8 + h]) * 1.4426950408889634f
                 - 28.853900817779268f);
    pbT[j] = vv;
  }
  __syncthreads();

  // persistent Q B-fragments: Q^T[dh][q], lane reads Q[q0+ql][16c+8hi .. +7]
  const unsigned short* Qrow = QP + ((long)(bh << 10) + q0 + ql) * 64;
  bf16x8 qf[4];
  #pragma unroll
  for (int c = 0; c < 4; ++c)
    qf[c] = *(const bf16x8*)(Qrow + c * 16 + hi * 8);

  const int cn = cnt[b];
  const int nt = (cn + 63) >> 6;
  const unsigned short* Brow = BUKP + ((long)((b << 10) + q0 + ql)) * 1024;
  const unsigned short* Vb0 = VCT + ((long)(bh << 6) + ql) * 1024;
  const unsigned short* Vb1 = Vb0 + (32 << 10);

  float lsum = 0.f;
  f32x16 oa0, oa1;
  #pragma unroll
  for (int i = 0; i < 16; ++i) { oa0[i] = 0.f; oa1[i] = 0.f; }

  for (int kt = w; kt < nt; kt += 4) {
    const int kb = kt << 6;
    #pragma unroll
    for (int s = 0; s < 2; ++s) {
      const int k32 = kb + (s << 5);
      // K A-fragments: K[k32+ql][16c+8hi .. +7]
      const unsigned short* Kr = KC + ((long)(bh << 10) + k32 + ql) * 64 + hi * 8;
      bf16x8 kf0 = *(const bf16x8*)(Kr);
      bf16x8 kf1 = *(const bf16x8*)(Kr + 16);
      bf16x8 kf2 = *(const bf16x8*)(Kr + 32);
      bf16x8 kf3 = *(const bf16x8*)(Kr + 48);
      // bucket regs (crow-permuted storage): 16 u16 = 2 x b128
      uint4 bk0 = *(const uint4*)(Brow + k32 + (hi << 4));
      uint4 bk1 = *(const uint4*)(Brow + k32 + (hi << 4) + 8);
      // V A-fragments: V^T[dblk*32+ql][k32+16t+8hi .. +7]
      bf16x8 vf00 = *(const bf16x8*)(Vb0 + k32 + hi * 8);
      bf16x8 vf01 = *(const bf16x8*)(Vb0 + k32 + 16 + hi * 8);
      bf16x8 vf10 = *(const bf16x8*)(Vb1 + k32 + hi * 8);
      bf16x8 vf11 = *(const bf16x8*)(Vb1 + k32 + 16 + hi * 8);

      // S^T = K Q^T over dh=64 (4 chained MFMA)
      f32x16 sa;
      #pragma unroll
      for (int i = 0; i < 16; ++i) sa[i] = 0.f;
      sa = __builtin_amdgcn_mfma_f32_32x32x16_bf16(kf0, qf[0], sa, 0, 0, 0);
      sa = __builtin_amdgcn_mfma_f32_32x32x16_bf16(kf1, qf[1], sa, 0, 0, 0);
      sa = __builtin_amdgcn_mfma_f32_32x32x16_bf16(kf2, qf[2], sa, 0, 0, 0);
      sa = __builtin_amdgcn_mfma_f32_32x32x16_bf16(kf3, qf[3], sa, 0, 0, 0);

      // p[r] = 2^(s*scl) * pbT[bucket]  (static max; exp ∥ gather)
      unsigned bw0[4] = {bk0.x, bk0.y, bk0.z, bk0.w};
      unsigned bw1[4] = {bk1.x, bk1.y, bk1.z, bk1.w};
      float p[16];
      #pragma unroll
      for (int r = 0; r < 8; ++r) {
        unsigned bv = (r & 1) ? (bw0[r >> 1] >> 16) : (bw0[r >> 1] & 0xffff);
        p[r] = exp2f(sa[r] * SCL) * pbT[bv];
      }
      #pragma unroll
      for (int r = 8; r < 16; ++r) {
        unsigned bv = (r & 1) ? (bw1[(r - 8) >> 1] >> 16) : (bw1[(r - 8) >> 1] & 0xffff);
        p[r] = exp2f(sa[r] * SCL) * pbT[bv];
      }
      lsum += (((p[0] + p[1]) + (p[2] + p[3])) + ((p[4] + p[5]) + (p[6] + p[7])))
            + (((p[8] + p[9]) + (p[10] + p[11])) + ((p[12] + p[13]) + (p[14] + p[15])));

      // rebuild PV B-fragments: per 16-k chunk t, 4 packs + 2 permlane swaps
      union U8 { bf16x8 v; unsigned u[4]; };
      unsigned x0 = f2bf(p[0]) | ((unsigned)f2bf(p[1]) << 16);
      unsigned x1 = f2bf(p[2]) | ((unsigned)f2bf(p[3]) << 16);
      unsigned y0 = f2bf(p[4]) | ((unsigned)f2bf(p[5]) << 16);
      unsigned y1 = f2bf(p[6]) | ((unsigned)f2bf(p[7]) << 16);
      pl32swap(x0, y0);
      pl32swap(x1, y1);
      U8 pu0; pu0.u[0] = x0; pu0.u[1] = x1; pu0.u[2] = y0; pu0.u[3] = y1;
      unsigned z0 = f2bf(p[8])  | ((unsigned)f2bf(p[9])  << 16);
      unsigned z1 = f2bf(p[10]) | ((unsigned)f2bf(p[11]) << 16);
      unsigned u0 = f2bf(p[12]) | ((unsigned)f2bf(p[13]) << 16);
      unsigned u1 = f2bf(p[14]) | ((unsigned)f2bf(p[15]) << 16);
      pl32swap(z0, u0);
      pl32swap(z1, u1);
      U8 pu1; pu1.u[0] = z0; pu1.u[1] = z1; pu1.u[2] = u0; pu1.u[3] = u1;

      // O^T += V^T P
      oa0 = __builtin_amdgcn_mfma_f32_32x32x16_bf16(vf00, pu0.v, oa0, 0, 0, 0);
      oa0 = __builtin_amdgcn_mfma_f32_32x32x16_bf16(vf01, pu1.v, oa0, 0, 0, 0);
      oa1 = __builtin_amdgcn_mfma_f32_32x32x16_bf16(vf10, pu0.v, oa1, 0, 0, 0);
      oa1 = __builtin_amdgcn_mfma_f32_32x32x16_bf16(vf11, pu1.v, oa1, 0, 0, 0);
    }
  }

  // lsum: add the partner half (lanes (q,0)+(q,1))
  {
    unsigned a = __float_as_uint(lsum), bcp = a;
    pl32swap(a, bcp);
    lsum = __uint_as_float(a) + __uint_as_float(bcp);
  }

  // merge 4 key-quarter partials (pure add — static max) via LDS
  __syncthreads();                    // all waves done reading pbT (aliased)
  #pragma unroll
  for (int r = 0; r < 16; ++r) {
    Omrg[w][r][lane] = oa0[r];
    Omrg[w][16 + r][lane] = oa1[r];
  }
  if (lane < 32) Lmrg[(w << 5) + lane] = lsum;
  __syncthreads();

  float lt = Lmrg[ql] + Lmrg[32 + ql] + Lmrg[64 + ql] + Lmrg[96 + ql];
  float linv = 1.f / lt;
  float os[8];
  #pragma unroll
  for (int j = 0; j < 8; ++j) {
    int rr = (w << 3) + j;
    os[j] = (Omrg[0][rr][lane] + Omrg[1][rr][lane] +
             Omrg[2][rr][lane] + Omrg[3][rr][lane]) * linv;
  }
  // store: wave w covers d = 32*(w>>1) + 16*(w&1) + 8*grp + 4*hi + j
  int qg = q0 + ql;
  long aobase = ((long)((b << 10) + qg)) * 512 + (h << 6);
  int dbase = ((w >> 1) << 5) + ((w & 1) << 4) + (hi << 2);
  uint2 st0, st1;
  st0.x = f2bf(os[0]) | ((unsigned)f2bf(os[1]) << 16);
  st0.y = f2bf(os[2]) | ((unsigned)f2bf(os[3]) << 16);
  st1.x = f2bf(os[4]) | ((unsigned)f2bf(os[5]) << 16);
  st1.y = f2bf(os[6]) | ((unsigned)f2bf(os[7]) << 16);
  *(uint2*)(AO + aobase + dbase) = st0;
  *(uint2*)(AO + aobase + dbase + 8) = st1;
}

// ---------------- output projection: out = AO @ Wo^T + bo (fp32 out) ------------
__global__ __launch_bounds__(256)
void k_gemm_out(const unsigned short* __restrict__ AO, const unsigned short* __restrict__ WO,
                const float* __restrict__ bo, float* __restrict__ out)
{
  __shared__ unsigned short ldsA[128 * 32];
  __shared__ unsigned short ldsB[64 * 32];
  int m0 = blockIdx.x * 128, n0 = blockIdx.y * 64;
  f32x4 acc[4][2];
  gemm_core64(AO, WO, m0, n0, ldsA, ldsB, acc);

  const int t = threadIdx.x, lane = t & 63, w = t >> 6;
  const int wm = (w >> 1) << 6, wn = (w & 1) << 5;
  const int l15 = lane & 15, l4 = lane >> 4;
  #pragma unroll
  for (int r = 0; r < 4; ++r)
    #pragma unroll
    for (int c = 0; c < 2; ++c)
      #pragma unroll
      for (int i = 0; i < 4; ++i) {
        int m = m0 + wm + r * 16 + (l4 << 2) + i;
        int n = n0 + wn + c * 16 + l15;
        out[(long)m * 512 + n] = acc[r][c][i] + bo[n];
      }
}

// ---------------- launch ---------------------------------------------------------
extern "C" void kernel_launch(void* const* d_in, const int* in_sizes, int n_in,
                              void* d_out, int out_size, void* d_ws, size_t ws_size,
                              hipStream_t stream) {
  const float* q      = (const float*)d_in[0];
  const float* k      = (const float*)d_in[1];
  const float* v      = (const float*)d_in[2];
  const float* coords = (const float*)d_in[3];
  const int*   mask   = (const int*)d_in[4];
  const float* Wq     = (const float*)d_in[5];
  const float* bq     = (const float*)d_in[6];
  const float* Wk     = (const float*)d_in[7];
  const float* bk     = (const float*)d_in[8];
  const float* Wv     = (const float*)d_in[9];
  const float* bv     = (const float*)d_in[10];
  const float* Wo     = (const float*)d_in[11];
  const float* bo     = (const float*)d_in[12];
  const float* rpe_x  = (const float*)d_in[13];
  const float* rpe_y  = (const float*)d_in[14];
  float* out = (float*)d_out;

  unsigned short* WQB  = (unsigned short*)d_ws;
  unsigned short* WKB  = WQB + 262144;
  unsigned short* WVB  = WKB + 262144;
  unsigned short* WOB  = WVB + 262144;
  unsigned short* XQ   = WOB + 262144;   // 3x2097152; dead after proj
  unsigned short* XK   = XQ + 2097152;
  unsigned short* XV   = XK + 2097152;
  unsigned short* QP   = XV + 2097152;
  unsigned short* KP   = QP + 2097152;
  unsigned short* VTMP = KP + 2097152;
  unsigned short* KC   = VTMP + 2097152;
  unsigned short* VCT  = KC + 2097152;
  unsigned short* AO   = VCT + 2097152;
  int* idxp            = (int*)(AO + 2097152);   // 4096 ints
  int* cntp            = idxp + 4096;            // 4 ints
  unsigned short* BUKP = XQ;   // alias: written after proj consumed XQ..XV

  k_cvt_scan<<<dim3(3588), dim3(256), 0, stream>>>(q, k, v, Wq, Wk, Wv, Wo, mask,
                                                   XQ, XK, XV, WQB, WKB, WVB, WOB,
                                                   idxp, cntp);
  k_gemm_proj<<<dim3(32, 8, 3), dim3(256), 0, stream>>>(XQ, XK, XV, WQB, WKB, WVB,
                                                        bq, bk, bv, QP, KP, VTMP);
  k_gather_buckets<<<dim3(16896), dim3(256), 0, stream>>>(KP, VTMP, coords, idxp, cntp,
                                                          KC, VCT, BUKP);
  k_attn<<<dim3(1024), dim3(256), 0, stream>>>(QP, KC, VCT, BUKP, cntp,
                                               rpe_x, rpe_y, AO);
  k_gemm_out<<<dim3(32, 8), dim3(256), 0, stream>>>(AO, WOB, bo, out);
}